// Round 16
// baseline (122.607 us; speedup 1.0000x reference)
//
#include <hip/hip_runtime.h>
#include <math.h>

// Problem dims (fixed by setup_inputs): B=1024, D=256, H=1024
#define Bsz 1024
#define Dsz 256
#define Hsz 1024

typedef unsigned short u16;
typedef __bf16 bf16x8 __attribute__((ext_vector_type(8)));
typedef float  f32x4  __attribute__((ext_vector_type(4)));

__device__ __forceinline__ float bf2f(u16 u) {
  unsigned v = ((unsigned)u) << 16;
  return __builtin_bit_cast(float, v);
}
__device__ __forceinline__ u16 f2bf(float f) {
  unsigned u = __builtin_bit_cast(unsigned, f);
  u += 0x7FFFu + ((u >> 16) & 1u);  // round-to-nearest-even
  return (u16)(u >> 16);
}

constexpr int LS = 72;          // LDS row stride (bf16): 144B -> staggered banks
constexpr int ATILE = 128 * LS; // A: 128-row tile (elems)
constexpr int BTILE = 64 * LS;  // B: 64-row tile (elems)

__device__ __forceinline__ bf16x8 frag(const u16* __restrict__ s, int row, int off) {
  union { uint4 u; bf16x8 b; } cv;
  cv.u = *reinterpret_cast<const uint4*>(&s[row * LS + off]);
  return cv.b;
}
#define MFMA __builtin_amdgcn_mfma_f32_16x16x32_bf16

// ---------------------------------------------------------------------------
// prep: casts/transposes + reg/ldj zeroing (896 blocks)
// ---------------------------------------------------------------------------
__device__ __forceinline__ void cast_chunk(const float* __restrict__ in,
                                           u16* __restrict__ out, int b, int t) {
  const int i = b * 256 + t;
  const float4 v = reinterpret_cast<const float4*>(in)[i];
  ushort4 o;
  o.x = f2bf(v.x); o.y = f2bf(v.y); o.z = f2bf(v.z); o.w = f2bf(v.w);
  *reinterpret_cast<ushort4*>(&out[(size_t)i * 4]) = o;
}

__device__ __forceinline__ void tr_tile(float (*tl)[65], const float* __restrict__ in,
                                        u16* __restrict__ out, int R, int C,
                                        int c0, int r0, int t) {
#pragma unroll
  for (int p = 0; p < 4; ++p) {
    const int r = p * 16 + (t >> 4);
    const int c = (t & 15) * 4;
    const float4 v = *reinterpret_cast<const float4*>(&in[(size_t)(r0 + r) * C + c0 + c]);
    tl[r][c] = v.x; tl[r][c + 1] = v.y; tl[r][c + 2] = v.z; tl[r][c + 3] = v.w;
  }
  __syncthreads();
#pragma unroll
  for (int p = 0; p < 4; ++p) {
    const int a = p * 16 + (t >> 4);
    const int b4 = (t & 15) * 4;
    ushort4 o;
    o.x = f2bf(tl[b4 + 0][a]); o.y = f2bf(tl[b4 + 1][a]);
    o.z = f2bf(tl[b4 + 2][a]); o.w = f2bf(tl[b4 + 3][a]);
    *reinterpret_cast<ushort4*>(&out[(size_t)(c0 + a) * R + r0 + b4]) = o;
  }
}

__global__ __launch_bounds__(256) void prep(const float* __restrict__ x,
                                            const float* __restrict__ W1,
                                            const float* __restrict__ W2,
                                            const float* __restrict__ W3,
                                            u16* __restrict__ xb,
                                            u16* __restrict__ W3b,
                                            u16* __restrict__ W1bT,
                                            u16* __restrict__ W2bT,
                                            u16* __restrict__ W3bT,
                                            float* __restrict__ ldj) {
  __shared__ float tl[64][65];
  const int b = blockIdx.x, t = threadIdx.x;
  if (b == 0) {
    for (int i = t; i < 2048; i += 256) ldj[i] = 0.0f;  // reg must be 0 (ldj stored later)
  }
  if (b < 256) {
    cast_chunk(x, xb, b, t);
  } else if (b < 512) {
    cast_chunk(W3, W3b, b - 256, t);
  } else if (b < 576) {
    const int tb = b - 512;  // W1 [D][H] -> W1bT [H][D]
    tr_tile(tl, W1, W1bT, Dsz, Hsz, (tb & 15) * 64, (tb >> 4) * 64, t);
  } else if (b < 832) {
    const int tb = b - 576;  // W2 [H][H] -> W2bT [H][H]
    tr_tile(tl, W2, W2bT, Hsz, Hsz, (tb & 15) * 64, (tb >> 4) * 64, t);
  } else {
    const int tb = b - 832;  // W3 [H][D] -> W3bT [D][H]
    tr_tile(tl, W3, W3bT, Hsz, Dsz, (tb & 3) * 64, (tb >> 2) * 64, t);
  }
}

// ---------------------------------------------------------------------------
// MFMA GEMM body — 128x64 block tile, 2-phase pipeline (r15-verified):
//   4 waves x (64x32) wave tiles: LDS reads/MFMA = 0.75 (vs 1.0 at 32x32),
//   barriers per MFMA halved. Double-buffered LDS, ONE barrier per K-iter,
//   loads issued right after the barrier so they overlap MFMA compute.
// SQA: h -> 1-h*h while staging A (d1 from H1b without a separate buffer).
// ---------------------------------------------------------------------------
enum { EPI_H1 = 0, EPI_AMAT = 1, EPI_H2 = 2, EPI_DX = 3, EPI_U = 4 };

template <int EPI, bool SQA>
__device__ __forceinline__ void gemm_body(
    int row0, int col0,
    u16* __restrict__ Asb, u16* __restrict__ Bsb,   // 2*ATILE / 2*BTILE dbuf
    const u16* __restrict__ A, const u16* __restrict__ Bt,
    int K, int ldo,
    float* __restrict__ fout, u16* __restrict__ bout,
    const u16* __restrict__ aux,
    const float* __restrict__ v1, const float* __restrict__ v2,
    const float* __restrict__ tptr) {
  const int t = threadIdx.x;
  const int lane = t & 63, wid = t >> 6;

  // A staging: 128 rows x 64 k; thread t -> row t>>1, 64B chunk at (t&1)*32
  const int am = t >> 1, ao = (t & 1) * 32;
  const size_t a_base = (size_t)(row0 + am) * K + ao;
  // B staging: 64 rows x 64 k; thread t -> row t>>2, 16B chunks at (t&3)*8, +32
  const int bm = t >> 2, bq = t & 3;
  const size_t b_base = (size_t)(col0 + bm) * K + bq * 8;

  uint4 ar[4], br[2];
  auto load_regs = [&](int k0) {
#pragma unroll
    for (int c = 0; c < 4; ++c)
      ar[c] = *reinterpret_cast<const uint4*>(&A[a_base + k0 + c * 8]);
    br[0] = *reinterpret_cast<const uint4*>(&Bt[b_base + k0]);
    br[1] = *reinterpret_cast<const uint4*>(&Bt[b_base + k0 + 32]);
  };
  auto sq_tr = [&](uint4 v) -> uint4 {
    u16* p = reinterpret_cast<u16*>(&v);
    uint4 o; u16* po = reinterpret_cast<u16*>(&o);
#pragma unroll
    for (int i = 0; i < 8; ++i) { const float h = bf2f(p[i]); po[i] = f2bf(1.0f - h * h); }
    return o;
  };
  auto store_lds = [&](int buf) {
    const int oa = buf * ATILE + am * LS + ao;
#pragma unroll
    for (int c = 0; c < 4; ++c)
      *reinterpret_cast<uint4*>(&Asb[oa + c * 8]) = SQA ? sq_tr(ar[c]) : ar[c];
    const int ob = buf * BTILE + bm * LS + bq * 8;
    *reinterpret_cast<uint4*>(&Bsb[ob +  0]) = br[0];
    *reinterpret_cast<uint4*>(&Bsb[ob + 32]) = br[1];
  };

  f32x4 acc[4][2] = {};
  const int mo = (wid >> 1) * 64, no = (wid & 1) * 32;  // wave tile 64x32
  const int fr = lane & 15, fg = lane >> 4;

  const int NK = K >> 6;
  load_regs(0);
  store_lds(0);
  int cur = 0;
  for (int it = 0; it < NK; ++it) {
    __syncthreads();                       // buf[cur] visible; buf[cur^1] free
    if (it + 1 < NK) load_regs((it + 1) << 6);  // in flight under compute
    const u16* Ac = Asb + cur * ATILE;
    const u16* Bc = Bsb + cur * BTILE;
#pragma unroll
    for (int ks = 0; ks < 64; ks += 32) {
      const int off = ks + fg * 8;
      const bf16x8 b0  = frag(Bc, no + fr, off);
      const bf16x8 b1v = frag(Bc, no + 16 + fr, off);
#pragma unroll
      for (int mi = 0; mi < 4; ++mi) {
        const bf16x8 a = frag(Ac, mo + mi * 16 + fr, off);
        acc[mi][0] = MFMA(a, b0,  acc[mi][0], 0, 0, 0);
        acc[mi][1] = MFMA(a, b1v, acc[mi][1], 0, 0, 0);
      }
    }
    if (it + 1 < NK) store_lds(cur ^ 1);   // waits vmcnt only for its own data
    cur ^= 1;
  }

  // C/D layout (m89-verified): col = lane&15, row = (lane>>4)*4 + reg
  const int cr = mo + fg * 4;  // + mi*16 + r  (block-local row)
  const int cc = no + fr;      // + ni*16      (block-local col)

  if (EPI == EPI_H1) {
    const float ts = tptr[0];
#pragma unroll
    for (int ni = 0; ni < 2; ++ni) {
      const int col = col0 + cc + ni * 16;
      const float add = v1[col] + ts * v2[col];
#pragma unroll
      for (int mi = 0; mi < 4; ++mi)
#pragma unroll
        for (int r = 0; r < 4; ++r) {
          const int row = row0 + cr + mi * 16 + r;
          bout[(size_t)row * Hsz + col] = f2bf(tanhf(acc[mi][ni][r] + add));
        }
    }
  } else if (EPI == EPI_AMAT) {
#pragma unroll
    for (int mi = 0; mi < 4; ++mi)
#pragma unroll
      for (int ni = 0; ni < 2; ++ni)
#pragma unroll
        for (int r = 0; r < 4; ++r) {
          const int row = row0 + cr + mi * 16 + r;
          const int col = col0 + cc + ni * 16;
          const float w2 = bf2f(aux[(size_t)row * Hsz + col]);  // W2bT[j][i] = W2[i][j]
          bout[(size_t)row * Hsz + col] = f2bf(w2 * acc[mi][ni][r]);
        }
  } else if (EPI == EPI_H2) {
#pragma unroll
    for (int ni = 0; ni < 2; ++ni) {
      const int col = col0 + cc + ni * 16;
      const float add = v1[col];
#pragma unroll
      for (int mi = 0; mi < 4; ++mi)
#pragma unroll
        for (int r = 0; r < 4; ++r) {
          const int row = row0 + cr + mi * 16 + r;
          bout[(size_t)row * Hsz + col] = f2bf(tanhf(acc[mi][ni][r] + add));
        }
    }
  } else if (EPI == EPI_DX) {
#pragma unroll
    for (int ni = 0; ni < 2; ++ni) {
      const int col = col0 + cc + ni * 16;
      const float add = v1[col];
#pragma unroll
      for (int mi = 0; mi < 4; ++mi)
#pragma unroll
        for (int r = 0; r < 4; ++r) {
          const int row = row0 + cr + mi * 16 + r;
          fout[(size_t)row * ldo + col] = acc[mi][ni][r] + add;
        }
    }
  } else {  // EPI_U: raw f32 U tile to workspace
#pragma unroll
    for (int ni = 0; ni < 2; ++ni) {
      const int col = col0 + cc + ni * 16;
#pragma unroll
      for (int mi = 0; mi < 4; ++mi)
#pragma unroll
        for (int r = 0; r < 4; ++r) {
          const int row = row0 + cr + mi * 16 + r;
          fout[(size_t)row * Hsz + col] = acc[mi][ni][r];
        }
    }
  }
}

// ---------------------------------------------------------------------------
// Phase B (256 blocks, 128x64 tiles): k1 (b<128) + k2 (b>=128)
// ---------------------------------------------------------------------------
__global__ __launch_bounds__(256) void phaseB(const u16* __restrict__ xb,
                                              const u16* __restrict__ W1bT,
                                              const u16* __restrict__ W3b,
                                              const u16* __restrict__ W2bT,
                                              u16* __restrict__ H1b,
                                              u16* __restrict__ AmatT,
                                              const float* __restrict__ b1,
                                              const float* __restrict__ tW,
                                              const float* __restrict__ t) {
  __shared__ u16 As[2 * ATILE];
  __shared__ u16 Bs[2 * BTILE];
  const int b = blockIdx.x;
  if (b < 128) {
    gemm_body<EPI_H1, false>((b >> 4) * 128, (b & 15) * 64, As, Bs,
                             xb, W1bT, Dsz, Hsz, nullptr, H1b, nullptr, b1, tW, t);
  } else {
    const int c = b - 128;
    gemm_body<EPI_AMAT, false>((c >> 4) * 128, (c & 15) * 64, As, Bs,
                               W3b, W1bT, Dsz, Hsz, nullptr, AmatT, W2bT,
                               nullptr, nullptr, nullptr);
  }
}

// ---------------------------------------------------------------------------
// Phase CU (256 blocks, 128x64 tiles): k3 (b<128) + k5a U=d1@Amat (b>=128),
// concurrent (disjoint write sets; both need only phaseB outputs).
// ---------------------------------------------------------------------------
__global__ __launch_bounds__(256) void phaseCU(const u16* __restrict__ H1b,
                                               const u16* __restrict__ W2bT,
                                               const u16* __restrict__ AmatT,
                                               u16* __restrict__ H2b,
                                               float* __restrict__ U,
                                               const float* __restrict__ b2) {
  __shared__ u16 As[2 * ATILE];
  __shared__ u16 Bs[2 * BTILE];
  const int b = blockIdx.x;
  if (b < 128) {
    gemm_body<EPI_H2, false>((b >> 4) * 128, (b & 15) * 64, As, Bs,
                             H1b, W2bT, Hsz, Hsz, nullptr, H2b, nullptr, b2,
                             nullptr, nullptr);
  } else {
    const int c = b - 128;
    gemm_body<EPI_U, true>((c >> 4) * 128, (c & 15) * 64, As, Bs,
                           H1b, AmatT, Hsz, Hsz, U, nullptr, nullptr,
                           nullptr, nullptr, nullptr);
  }
}

// ---------------------------------------------------------------------------
// Phase D (96 blocks): k4 dx (b<32, 128x64 tiles) + k5b masked reduce (b>=32).
// k5b: ldj[row] = sum_j U[row][j] * (1 - h2[row][j]^2), direct store (no
// atomics). 64 blocks x 16 rows; 16 threads/row, coalesced float4 strides.
// ---------------------------------------------------------------------------
__global__ __launch_bounds__(256) void phaseD(const u16* __restrict__ H2b,
                                              const u16* __restrict__ W3bT,
                                              const float* __restrict__ U,
                                              float* __restrict__ dx,
                                              float* __restrict__ ldj,
                                              const float* __restrict__ b3) {
  const int b = blockIdx.x;
  if (b < 32) {
    __shared__ u16 As[2 * ATILE];
    __shared__ u16 Bs[2 * BTILE];
    gemm_body<EPI_DX, false>((b >> 2) * 128, (b & 3) * 64, As, Bs,
                             H2b, W3bT, Hsz, Dsz, dx, nullptr, nullptr, b3,
                             nullptr, nullptr);
  } else {
    __shared__ float sr[16][17];
    const int t = threadIdx.x;
    const int row = (b - 32) * 16 + (t >> 4);
    const int c0 = (t & 15) * 4;
    float s = 0.0f;
#pragma unroll
    for (int k = 0; k < 16; ++k) {
      const int c = c0 + k * 64;
      const float4 u4 = *reinterpret_cast<const float4*>(&U[(size_t)row * Hsz + c]);
      const ushort4 h4 = *reinterpret_cast<const ushort4*>(&H2b[(size_t)row * Hsz + c]);
      const float h0 = bf2f(h4.x), h1 = bf2f(h4.y), h2 = bf2f(h4.z), h3 = bf2f(h4.w);
      s += u4.x * (1.0f - h0 * h0) + u4.y * (1.0f - h1 * h1)
         + u4.z * (1.0f - h2 * h2) + u4.w * (1.0f - h3 * h3);
    }
    sr[t >> 4][t & 15] = s;
    __syncthreads();
    if (t < 16) {
      float tot = 0.0f;
#pragma unroll
      for (int u = 0; u < 16; ++u) tot += sr[t][u];
      ldj[(b - 32) * 16 + t] = tot;
    }
  }
}

// ---------------------------------------------------------------------------
// Launch: 4 dispatches.
// ldj[b] = sum_{i,j} d1[b,i]*(W2.*N)[i,j]*d2[b,j],  N = (W3@W1)^T.
// AmatT[j][i] = W2[i][j]*(W3@W1)[j][i] is k2's natural tile orientation AND
// the Bt layout k5a consumes.
// ---------------------------------------------------------------------------
extern "C" void kernel_launch(void* const* d_in, const int* in_sizes, int n_in,
                              void* d_out, int out_size, void* d_ws, size_t ws_size,
                              hipStream_t stream) {
  const float* x  = (const float*)d_in[0];
  const float* t  = (const float*)d_in[1];
  const float* W1 = (const float*)d_in[4];
  const float* b1 = (const float*)d_in[5];
  const float* tW = (const float*)d_in[6];
  const float* W2 = (const float*)d_in[7];
  const float* b2 = (const float*)d_in[8];
  const float* W3 = (const float*)d_in[9];
  const float* b3 = (const float*)d_in[10];

  float* out = (float*)d_out;
  float* dx  = out;                      // [B,D]
  float* ldj = out + (size_t)Bsz * Dsz;  // [B], then reg [B]

  u16* w = (u16*)d_ws;
  u16* xb    = w;                    // [B][D]    262144
  u16* W1bT  = xb    + 262144;       // [H][D]    (= W1^T)
  u16* W3b   = W1bT  + 262144;       // [H][D]
  u16* W3bT  = W3b   + 262144;       // [D][H]    (= W3^T)
  u16* W2bT  = W3bT  + 262144;       // [H][H]    (= W2^T)
  u16* AmatT = W2bT  + 1048576;      // [H][H]
  u16* H1b   = AmatT + 1048576;      // [B][H]
  u16* H2b   = H1b   + 1048576;      // [B][H]
  float* U   = (float*)(H2b + 1048576);  // [B][H] f32 (4 MB; 14.5 MB total)

  const dim3 blk(256);
  prep   <<<dim3(896), blk, 0, stream>>>(x, W1, W2, W3, xb, W3b, W1bT, W2bT, W3bT, ldj);
  phaseB <<<dim3(256), blk, 0, stream>>>(xb, W1bT, W3b, W2bT, H1b, AmatT, b1, tW, t);
  phaseCU<<<dim3(256), blk, 0, stream>>>(H1b, W2bT, AmatT, H2b, U, b2);
  phaseD <<<dim3(96),  blk, 0, stream>>>(H2b, W3bT, U, dx, ldj, b3);
}